// Round 13
// baseline (627.323 us; speedup 1.0000x reference)
//
#include <hip/hip_runtime.h>
#include <hip/hip_bf16.h>

#define BB 16
#define NN 512
#define DD 64
#define BN_ROWS (BB * NN)   // 8192

// R13: canonical semantics (verified 5x, 3 codegens), inputs fp32 (proven via
// R2/R10 NaN forensics), OUTPUT FP32 (harness contract: reference output dtype
// = float32; the 12-round "decorrelation" was bf16-written-into-fp32-buffer).
// ws: [0, 2MB) x_out fp32 | [2MB, +512B) stats[128]

__device__ __forceinline__ float safe_tanh(float x) {
    x = fminf(9.0f, fmaxf(-9.0f, x));
    const float e = expf(2.0f * x);
    return (e - 1.0f) / (e + 1.0f);
}

__global__ __launch_bounds__(128) void init_kernel(float* __restrict__ stats) {
    if (threadIdx.x < 128) stats[threadIdx.x] = 0.0f;
}

// One block per (b,i): scores, softmax over j, aggregate, projections.
// x_out = agg @ W_with.T + b_with + x @ W_without.T + b_without
__global__ __launch_bounds__(256) void attn_kernel(
    const float* __restrict__ x,  const float* __restrict__ Wp,
    const float* __restrict__ bp, const float* __restrict__ aw,
    const float* __restrict__ W1, const float* __restrict__ b1,
    const float* __restrict__ W2, const float* __restrict__ b2,
    float* __restrict__ xout, float* __restrict__ stats)
{
    __shared__ __align__(16) float sW[DD * DD];   // W_att_proj row-major (o,d)
    __shared__ float s_bp[DD], s_aw[DD], s_xi[DD];
    __shared__ float s_a[NN];
    __shared__ float red[256];
    __shared__ float part[4][DD];
    __shared__ float s_agg[DD];

    const int blk = blockIdx.x;            // 0..8191
    const int b = blk >> 9;
    const int i = blk & (NN - 1);
    const int t = threadIdx.x;
    const float* __restrict__ xb = x + (size_t)b * NN * DD;

    {   // stage W_att_proj into LDS
        const float4* __restrict__ src = (const float4*)Wp;
        float4* __restrict__ dst = (float4*)sW;
        for (int k = t; k < DD * DD / 4; k += 256) dst[k] = src[k];
    }
    if (t < DD) {
        s_bp[t] = bp[t];
        s_aw[t] = aw[t];
        s_xi[t] = xb[(size_t)i * DD + t];
    }
    __syncthreads();

    // ---- scores: thread t handles j = t and j = t + 256 ----
    float q0[DD], q1[DD];
    {
        const float4* __restrict__ r0 = (const float4*)(xb + (size_t)t * DD);
        const float4* __restrict__ r1 = (const float4*)(xb + (size_t)(t + 256) * DD);
        for (int k = 0; k < DD / 4; ++k) {
            const float4 a = r0[k], c = r1[k];
            q0[4*k+0] = a.x; q0[4*k+1] = a.y; q0[4*k+2] = a.z; q0[4*k+3] = a.w;
            q1[4*k+0] = c.x; q1[4*k+1] = c.y; q1[4*k+2] = c.z; q1[4*k+3] = c.w;
        }
        for (int d = 0; d < DD; ++d) { q0[d] *= s_xi[d]; q1[d] *= s_xi[d]; }
    }
    float s0 = 0.0f, s1 = 0.0f;
    for (int o = 0; o < DD; ++o) {
        const float4* __restrict__ w4 = (const float4*)(sW + o * DD); // broadcast
        float v0 = s_bp[o], v1 = v0;
        for (int k = 0; k < DD / 4; ++k) {
            const float4 w = w4[k];
            v0 = fmaf(w.x, q0[4*k+0], v0); v1 = fmaf(w.x, q1[4*k+0], v1);
            v0 = fmaf(w.y, q0[4*k+1], v0); v1 = fmaf(w.y, q1[4*k+1], v1);
            v0 = fmaf(w.z, q0[4*k+2], v0); v1 = fmaf(w.z, q1[4*k+2], v1);
            v0 = fmaf(w.w, q0[4*k+3], v0); v1 = fmaf(w.w, q1[4*k+3], v1);
        }
        const float awo = s_aw[o];
        s0 = fmaf(awo, safe_tanh(v0), s0);
        s1 = fmaf(awo, safe_tanh(v1), s1);
    }

    // ---- softmax over the 512 scores (axis = j) ----
    red[t] = fmaxf(s0, s1);
    __syncthreads();
    for (int off = 128; off > 0; off >>= 1) {
        if (t < off) red[t] = fmaxf(red[t], red[t + off]);
        __syncthreads();
    }
    const float gmax = red[0];
    __syncthreads();
    const float e0 = expf(s0 - gmax);
    const float e1 = expf(s1 - gmax);
    red[t] = e0 + e1;
    __syncthreads();
    for (int off = 128; off > 0; off >>= 1) {
        if (t < off) red[t] += red[t + off];
        __syncthreads();
    }
    const float inv = 1.0f / red[0];
    s_a[t] = e0 * inv;
    s_a[t + 256] = e1 * inv;
    __syncthreads();

    // ---- aggregate: wave w covers 128 j's; lane = channel d ----
    const int w = t >> 6, lane = t & 63;
    float acc = 0.0f;
    for (int jj = 0; jj < 128; ++jj) {
        const int j = w * 128 + jj;
        acc = fmaf(s_a[j], xb[(size_t)j * DD + lane], acc);
    }
    part[w][lane] = acc;
    __syncthreads();
    if (t < DD) s_agg[t] = part[0][t] + part[1][t] + part[2][t] + part[3][t];
    __syncthreads();

    // ---- projections + fp32 store + BN stats (threads 0..63, o = t) ----
    if (t < DD) {
        const int o = t;
        const float* __restrict__ w1 = W1 + o * DD;   // agg @ W_with.T
        const float* __restrict__ w2 = W2 + o * DD;   // x   @ W_without.T
        float v = b1[o] + b2[o];
        for (int d = 0; d < DD; ++d)
            v = fmaf(w1[d], s_agg[d], fmaf(w2[d], s_xi[d], v));
        xout[(size_t)blk * DD + o] = v;
        atomicAdd(&stats[o], v);
        atomicAdd(&stats[64 + o], v * v);
    }
}

// BN (batch stats, biased var) + selu -> FP32 out, canonical (b,i,o) order.
__global__ __launch_bounds__(256) void final_kernel(
    const float* __restrict__ xout, const float* __restrict__ stats,
    const float* __restrict__ gamma, const float* __restrict__ beta,
    float* __restrict__ out)
{
    __shared__ float smu[DD], sga[DD], sbe[DD];
    if (threadIdx.x < DD) {
        const int o = threadIdx.x;
        const float mean = stats[o] * (1.0f / BN_ROWS);
        const float var  = stats[64 + o] * (1.0f / BN_ROWS) - mean * mean;
        smu[o] = mean;
        sga[o] = gamma[o] / sqrtf(var + 1e-5f);
        sbe[o] = beta[o];
    }
    __syncthreads();
    const int stride = gridDim.x * 256;
    for (int idx = blockIdx.x * 256 + threadIdx.x; idx < BN_ROWS * DD; idx += stride) {
        const int o = idx & 63;
        const float nrm = (xout[idx] - smu[o]) * sga[o] + sbe[o];
        const float res = nrm > 0.0f
            ? 1.0507009873554805f * nrm
            : 1.7580993408473766f * expm1f(nrm);
        out[idx] = res;                     // fp32 store
    }
}

extern "C" void kernel_launch(void* const* d_in, const int* in_sizes, int n_in,
                              void* d_out, int out_size, void* d_ws, size_t ws_size,
                              hipStream_t stream)
{
    const float* x  = (const float*)d_in[0];
    const float* Wp = (const float*)d_in[1];  // W_att_proj
    const float* bp = (const float*)d_in[2];  // b_att_proj
    const float* aw = (const float*)d_in[3];  // att_weight
    const float* W1 = (const float*)d_in[4];  // W_with
    const float* b1 = (const float*)d_in[5];  // b_with
    const float* W2 = (const float*)d_in[6];  // W_without
    const float* b2 = (const float*)d_in[7];  // b_without
    const float* ga = (const float*)d_in[8];  // gamma
    const float* be = (const float*)d_in[9];  // beta

    float* xout  = (float*)d_ws;                        // 2 MB fp32
    float* stats = xout + (size_t)BN_ROWS * DD;         // 128 floats
    float* out   = (float*)d_out;                       // FP32 output

    init_kernel<<<1, 128, 0, stream>>>(stats);
    attn_kernel<<<BN_ROWS, 256, 0, stream>>>(x, Wp, bp, aw, W1, b1, W2, b2, xout, stats);
    final_kernel<<<512, 256, 0, stream>>>(xout, stats, ga, be, out);
}

// Round 14
// 309.084 us; speedup vs baseline: 2.0296x; 2.0296x over previous
//
#include <hip/hip_runtime.h>
#include <hip/hip_bf16.h>

#define BB 16
#define NN 512
#define DD 64
#define BN_ROWS (BB * NN)   // 8192

typedef unsigned short ushort;
typedef unsigned int uint;
typedef short bf16x8 __attribute__((ext_vector_type(8)));   // 8 bf16 = 4 VGPRs
typedef float f32x4  __attribute__((ext_vector_type(4)));   // MFMA acc

// fp32 -> bf16 bits, round-to-nearest-even
__device__ __forceinline__ short f2bf(float f) {
    union { float f; uint u; } c; c.f = f;
    const uint u = c.u;
    return (short)((u + 0x7fffu + ((u >> 16) & 1u)) >> 16);
}

// tanh via native exp2/rcp: t = 1 - 2/(e^{2x}+1)
__device__ __forceinline__ float fast_tanh(float x) {
    x = fminf(9.0f, fmaxf(-9.0f, x));
    const float e = __builtin_amdgcn_exp2f(x * 2.885390081777927f); // 2x*log2(e)
    return 1.0f - 2.0f * __builtin_amdgcn_rcpf(e + 1.0f);
}

__global__ __launch_bounds__(128) void init_kernel(float* __restrict__ stats) {
    if (threadIdx.x < 128) stats[threadIdx.x] = 0.0f;
}

// One block per (b,i). Score GEMM via bf16 MFMA:
//   D[o][j] = bp[o] + sum_d Wp[o][d] * (xi[d]*xj[d]);  s[j] = sum_o aw[o]*tanh(D)
// Then softmax over j, aggregate, projections, fp32 x_out + BN stats.
__global__ __launch_bounds__(256) void attn_kernel(
    const float* __restrict__ x,  const float* __restrict__ Wp,
    const float* __restrict__ bp, const float* __restrict__ aw,
    const float* __restrict__ W1, const float* __restrict__ b1,
    const float* __restrict__ W2, const float* __restrict__ b2,
    float* __restrict__ xout, float* __restrict__ stats)
{
    __shared__ __align__(16) ushort sWb[DD * DD];   // Wp bf16, row-major [o][d], 8KB
    __shared__ float s_bp[DD], s_aw[DD], s_xi[DD];
    __shared__ float s_a[NN];
    __shared__ float red[256];
    __shared__ float part[4][DD];
    __shared__ float s_agg[DD];

    const int blk = blockIdx.x;            // 0..8191
    const int b = blk >> 9;
    const int i = blk & (NN - 1);
    const int t = threadIdx.x;
    const float* __restrict__ xb = x + (size_t)b * NN * DD;

    // stage Wp as bf16 into LDS + small vectors
    for (int k = t; k < DD * DD; k += 256) sWb[k] = (ushort)f2bf(Wp[k]);
    if (t < DD) {
        s_bp[t] = bp[t];
        s_aw[t] = aw[t];
        s_xi[t] = xb[(size_t)i * DD + t];
    }
    __syncthreads();

    const int wv = t >> 6;           // wave 0..3 (owns j in [wv*128, wv*128+128))
    const int lane = t & 63;
    const int qd = lane >> 4;        // quad 0..3
    const int ln = lane & 15;

    // A fragments: A[m=ln][k=qd*8+i], m-tile mt, k-step ks. Loaded once.
    bf16x8 afrag[4][2];
    #pragma unroll
    for (int mt = 0; mt < 4; ++mt)
        #pragma unroll
        for (int ks = 0; ks < 2; ++ks)
            afrag[mt][ks] = *(const bf16x8*)(&sWb[(mt * 16 + ln) * DD + ks * 32 + qd * 8]);

    // per-lane xi slice, bias and att-weight values for this lane's output rows
    float xiv[2][8];
    #pragma unroll
    for (int ks = 0; ks < 2; ++ks)
        #pragma unroll
        for (int e = 0; e < 8; ++e) xiv[ks][e] = s_xi[ks * 32 + qd * 8 + e];
    float bpv[4][4], awv[4][4];
    #pragma unroll
    for (int mt = 0; mt < 4; ++mt)
        #pragma unroll
        for (int r = 0; r < 4; ++r) {
            const int o = mt * 16 + qd * 4 + r;
            bpv[mt][r] = s_bp[o];
            awv[mt][r] = s_aw[o];
        }

    // ---- score GEMM: 8 n-tiles of 16 j's per wave ----
    #pragma unroll 2
    for (int nt = 0; nt < 8; ++nt) {
        const int j = wv * 128 + nt * 16 + ln;
        const float* __restrict__ xr = xb + (size_t)j * DD;

        // B fragments: B[k=qd*8+e][n=ln] = xi[d]*xj[d], d = ks*32+qd*8+e
        bf16x8 bfrag[2];
        #pragma unroll
        for (int ks = 0; ks < 2; ++ks) {
            const float4 p0 = *(const float4*)(xr + ks * 32 + qd * 8);
            const float4 p1 = *(const float4*)(xr + ks * 32 + qd * 8 + 4);
            bf16x8 bf;
            bf[0] = f2bf(p0.x * xiv[ks][0]); bf[1] = f2bf(p0.y * xiv[ks][1]);
            bf[2] = f2bf(p0.z * xiv[ks][2]); bf[3] = f2bf(p0.w * xiv[ks][3]);
            bf[4] = f2bf(p1.x * xiv[ks][4]); bf[5] = f2bf(p1.y * xiv[ks][5]);
            bf[6] = f2bf(p1.z * xiv[ks][6]); bf[7] = f2bf(p1.w * xiv[ks][7]);
            bfrag[ks] = bf;
        }

        float sj = 0.0f;
        #pragma unroll
        for (int mt = 0; mt < 4; ++mt) {
            f32x4 acc = { bpv[mt][0], bpv[mt][1], bpv[mt][2], bpv[mt][3] };
            acc = __builtin_amdgcn_mfma_f32_16x16x32_bf16(afrag[mt][0], bfrag[0], acc, 0, 0, 0);
            acc = __builtin_amdgcn_mfma_f32_16x16x32_bf16(afrag[mt][1], bfrag[1], acc, 0, 0, 0);
            // lane holds D[o = mt*16+qd*4+r][j], r=0..3
            #pragma unroll
            for (int r = 0; r < 4; ++r)
                sj = fmaf(awv[mt][r], fast_tanh(acc[r]), sj);
        }
        // reduce partial s over the 4 quads (same j = same ln)
        sj += __shfl_xor(sj, 16);
        sj += __shfl_xor(sj, 32);
        if (qd == 0) s_a[j] = sj;
    }
    __syncthreads();

    // ---- softmax over 512 scores (axis = j) ----
    const float s0 = s_a[t], s1 = s_a[t + 256];
    red[t] = fmaxf(s0, s1);
    __syncthreads();
    for (int off = 128; off > 0; off >>= 1) {
        if (t < off) red[t] = fmaxf(red[t], red[t + off]);
        __syncthreads();
    }
    const float gmax = red[0];
    __syncthreads();
    const float e0 = expf(s0 - gmax);
    const float e1 = expf(s1 - gmax);
    red[t] = e0 + e1;
    __syncthreads();
    for (int off = 128; off > 0; off >>= 1) {
        if (t < off) red[t] += red[t + off];
        __syncthreads();
    }
    const float inv = 1.0f / red[0];
    s_a[t] = e0 * inv;
    s_a[t + 256] = e1 * inv;
    __syncthreads();

    // ---- aggregate: wave wv covers 128 j's; lane = channel d ----
    float acc = 0.0f;
    for (int jj = 0; jj < 128; ++jj) {
        const int j = wv * 128 + jj;
        acc = fmaf(s_a[j], xb[(size_t)j * DD + lane], acc);
    }
    part[wv][lane] = acc;
    __syncthreads();
    if (t < DD) s_agg[t] = part[0][t] + part[1][t] + part[2][t] + part[3][t];
    __syncthreads();

    // ---- projections + fp32 store + BN stats (threads 0..63, o = t) ----
    if (t < DD) {
        const int o = t;
        const float* __restrict__ w1 = W1 + o * DD;   // agg @ W_with.T
        const float* __restrict__ w2 = W2 + o * DD;   // x   @ W_without.T
        float v = b1[o] + b2[o];
        for (int d = 0; d < DD; ++d)
            v = fmaf(w1[d], s_agg[d], fmaf(w2[d], s_xi[d], v));
        xout[(size_t)blk * DD + o] = v;
        atomicAdd(&stats[o], v);
        atomicAdd(&stats[64 + o], v * v);
    }
}

// BN (batch stats, biased var) + selu -> FP32 out, canonical (b,i,o) order.
__global__ __launch_bounds__(256) void final_kernel(
    const float* __restrict__ xout, const float* __restrict__ stats,
    const float* __restrict__ gamma, const float* __restrict__ beta,
    float* __restrict__ out)
{
    __shared__ float smu[DD], sga[DD], sbe[DD];
    if (threadIdx.x < DD) {
        const int o = threadIdx.x;
        const float mean = stats[o] * (1.0f / BN_ROWS);
        const float var  = stats[64 + o] * (1.0f / BN_ROWS) - mean * mean;
        smu[o] = mean;
        sga[o] = gamma[o] / sqrtf(var + 1e-5f);
        sbe[o] = beta[o];
    }
    __syncthreads();
    const int stride = gridDim.x * 256;
    for (int idx = blockIdx.x * 256 + threadIdx.x; idx < BN_ROWS * DD; idx += stride) {
        const int o = idx & 63;
        const float nrm = (xout[idx] - smu[o]) * sga[o] + sbe[o];
        const float res = nrm > 0.0f
            ? 1.0507009873554805f * nrm
            : 1.7580993408473766f * expm1f(nrm);
        out[idx] = res;
    }
}

extern "C" void kernel_launch(void* const* d_in, const int* in_sizes, int n_in,
                              void* d_out, int out_size, void* d_ws, size_t ws_size,
                              hipStream_t stream)
{
    const float* x  = (const float*)d_in[0];
    const float* Wp = (const float*)d_in[1];  // W_att_proj
    const float* bp = (const float*)d_in[2];  // b_att_proj
    const float* aw = (const float*)d_in[3];  // att_weight
    const float* W1 = (const float*)d_in[4];  // W_with
    const float* b1 = (const float*)d_in[5];  // b_with
    const float* W2 = (const float*)d_in[6];  // W_without
    const float* b2 = (const float*)d_in[7];  // b_without
    const float* ga = (const float*)d_in[8];  // gamma
    const float* be = (const float*)d_in[9];  // beta

    float* xout  = (float*)d_ws;                        // 2 MB fp32
    float* stats = xout + (size_t)BN_ROWS * DD;         // 128 floats
    float* out   = (float*)d_out;                       // fp32 output

    init_kernel<<<1, 128, 0, stream>>>(stats);
    attn_kernel<<<BN_ROWS, 256, 0, stream>>>(x, Wp, bp, aw, W1, b1, W2, b2, xout, stats);
    final_kernel<<<512, 256, 0, stream>>>(xout, stats, ga, be, out);
}

// Round 15
// 297.696 us; speedup vs baseline: 2.1073x; 1.0383x over previous
//
#include <hip/hip_runtime.h>
#include <hip/hip_bf16.h>

#define BB 16
#define NN 512
#define DD 64
#define BN_ROWS (BB * NN)   // 8192

typedef unsigned short ushort;
typedef unsigned int uint;
typedef short bf16x8 __attribute__((ext_vector_type(8)));   // 8 bf16 = 4 VGPRs
typedef float f32x4  __attribute__((ext_vector_type(4)));   // MFMA acc

// ws layout: [0, 2MB) xout fp32 | [+512B) stats[128] | [+8KB) Wp bf16 frag-ordered

// fp32 -> bf16 bits, round-to-nearest-even (prep kernel only)
__device__ __forceinline__ short f2bf(float f) {
    union { float f; uint u; } c; c.f = f;
    const uint u = c.u;
    return (short)((u + 0x7fffu + ((u >> 16) & 1u)) >> 16);
}

// pack two fp32 -> two bf16 (round-half-up) in one v_perm_b32
__device__ __forceinline__ uint pkbf2(float lo, float hi) {
    union { float f; uint u; } a, b; a.f = lo; b.f = hi;
    return __builtin_amdgcn_perm(b.u + 0x8000u, a.u + 0x8000u, 0x07060302u);
}

// tanh via native exp2/rcp: t = 1 - 2/(e^{2x}+1)
__device__ __forceinline__ float fast_tanh(float x) {
    x = fminf(9.0f, fmaxf(-9.0f, x));
    const float e = __builtin_amdgcn_exp2f(x * 2.885390081777927f); // 2x*log2(e)
    return 1.0f - 2.0f * __builtin_amdgcn_rcpf(e + 1.0f);
}

// One-time: Wp -> bf16 in MFMA A-fragment order; zero BN stats.
// frag addr: ((mt*2+ks)*64 + lane)*8 + e  where o=mt*16+ln, d=ks*32+qd*8+e, lane=qd*16+ln
__global__ __launch_bounds__(256) void prep_kernel(
    const float* __restrict__ Wp, ushort* __restrict__ wpf,
    float* __restrict__ stats)
{
    const int k = blockIdx.x * 256 + threadIdx.x;   // grid 16 -> 4096
    const int o = k >> 6, d = k & 63;
    const int mt = o >> 4, ln = o & 15;
    const int ks = d >> 5, qd = (d >> 3) & 3, e = d & 7;
    wpf[(((mt * 2 + ks) * 64) + (qd * 16 + ln)) * 8 + e] = (ushort)f2bf(Wp[k]);
    if (k < 128) stats[k] = 0.0f;
}

// One block per (b,i). Score GEMM via bf16 MFMA, fragment A from ws (no LDS).
__global__ __launch_bounds__(256) void attn_kernel(
    const float* __restrict__ x,  const ushort* __restrict__ wpf,
    const float* __restrict__ bp, const float* __restrict__ aw,
    const float* __restrict__ W1, const float* __restrict__ b1,
    const float* __restrict__ W2, const float* __restrict__ b2,
    float* __restrict__ xout, float* __restrict__ stats)
{
    __shared__ float s_bp[DD], s_aw[DD], s_xi[DD];
    __shared__ float s_a[NN];
    __shared__ float wred[4];
    __shared__ float part[4][DD];
    __shared__ float s_agg[DD];

    const int blk = blockIdx.x;            // 0..8191
    const int b = blk >> 9;
    const int i = blk & (NN - 1);
    const int t = threadIdx.x;
    const float* __restrict__ xb = x + (size_t)b * NN * DD;

    if (t < DD) {
        s_bp[t] = bp[t];
        s_aw[t] = aw[t];
        s_xi[t] = xb[(size_t)i * DD + t];
    }
    __syncthreads();

    const int wv = t >> 6;           // wave 0..3 (owns j in [wv*128, wv*128+128))
    const int lane = t & 63;
    const int qd = lane >> 4;        // quad 0..3
    const int ln = lane & 15;

    // A fragments: coalesced 16B loads from frag-ordered ws (L2-hot, once/block)
    bf16x8 afrag[4][2];
    #pragma unroll
    for (int mt = 0; mt < 4; ++mt)
        #pragma unroll
        for (int ks = 0; ks < 2; ++ks)
            afrag[mt][ks] = *(const bf16x8*)(wpf + (((mt * 2 + ks) * 64) + lane) * 8);

    float xiv[2][8];
    #pragma unroll
    for (int ks = 0; ks < 2; ++ks)
        #pragma unroll
        for (int e = 0; e < 8; ++e) xiv[ks][e] = s_xi[ks * 32 + qd * 8 + e];
    float bpv[4][4], awv[4][4];
    #pragma unroll
    for (int mt = 0; mt < 4; ++mt)
        #pragma unroll
        for (int r = 0; r < 4; ++r) {
            const int o = mt * 16 + qd * 4 + r;
            bpv[mt][r] = s_bp[o];
            awv[mt][r] = s_aw[o];
        }

    // ---- score GEMM: 8 n-tiles of 16 j's per wave ----
    #pragma unroll 2
    for (int nt = 0; nt < 8; ++nt) {
        const int j = wv * 128 + nt * 16 + ln;
        const float* __restrict__ xr = xb + (size_t)j * DD;

        bf16x8 bfrag[2];
        #pragma unroll
        for (int ks = 0; ks < 2; ++ks) {
            const float4 p0 = *(const float4*)(xr + ks * 32 + qd * 8);
            const float4 p1 = *(const float4*)(xr + ks * 32 + qd * 8 + 4);
            union { bf16x8 v; uint u[4]; } bf;
            bf.u[0] = pkbf2(p0.x * xiv[ks][0], p0.y * xiv[ks][1]);
            bf.u[1] = pkbf2(p0.z * xiv[ks][2], p0.w * xiv[ks][3]);
            bf.u[2] = pkbf2(p1.x * xiv[ks][4], p1.y * xiv[ks][5]);
            bf.u[3] = pkbf2(p1.z * xiv[ks][6], p1.w * xiv[ks][7]);
            bfrag[ks] = bf.v;
        }

        float sj = 0.0f;
        #pragma unroll
        for (int mt = 0; mt < 4; ++mt) {
            f32x4 acc = { bpv[mt][0], bpv[mt][1], bpv[mt][2], bpv[mt][3] };
            acc = __builtin_amdgcn_mfma_f32_16x16x32_bf16(afrag[mt][0], bfrag[0], acc, 0, 0, 0);
            acc = __builtin_amdgcn_mfma_f32_16x16x32_bf16(afrag[mt][1], bfrag[1], acc, 0, 0, 0);
            #pragma unroll
            for (int r = 0; r < 4; ++r)
                sj = fmaf(awv[mt][r], fast_tanh(acc[r]), sj);
        }
        sj += __shfl_xor(sj, 16);
        sj += __shfl_xor(sj, 32);
        if (qd == 0) s_a[j] = sj;
    }
    __syncthreads();

    // ---- softmax over 512 scores: shuffle reduce, 3 barriers ----
    const float s0 = s_a[t], s1 = s_a[t + 256];
    float m = fmaxf(s0, s1);
    #pragma unroll
    for (int off = 1; off < 64; off <<= 1) m = fmaxf(m, __shfl_xor(m, off));
    if (lane == 0) wred[wv] = m;
    __syncthreads();
    const float gmax = fmaxf(fmaxf(wred[0], wred[1]), fmaxf(wred[2], wred[3]));
    __syncthreads();
    const float e0 = __builtin_amdgcn_exp2f((s0 - gmax) * 1.4426950408889634f);
    const float e1 = __builtin_amdgcn_exp2f((s1 - gmax) * 1.4426950408889634f);
    float sm = e0 + e1;
    #pragma unroll
    for (int off = 1; off < 64; off <<= 1) sm += __shfl_xor(sm, off);
    if (lane == 0) wred[wv] = sm;
    __syncthreads();
    const float inv = 1.0f / (wred[0] + wred[1] + wred[2] + wred[3]);
    s_a[t] = e0 * inv;
    s_a[t + 256] = e1 * inv;
    __syncthreads();

    // ---- aggregate: wave wv covers 128 j's; lane = channel d; 4-way ILP ----
    float a0 = 0.0f, a1 = 0.0f, a2 = 0.0f, a3 = 0.0f;
    for (int jj = 0; jj < 128; jj += 4) {
        const int j = wv * 128 + jj;
        a0 = fmaf(s_a[j],     xb[(size_t)(j)     * DD + lane], a0);
        a1 = fmaf(s_a[j + 1], xb[(size_t)(j + 1) * DD + lane], a1);
        a2 = fmaf(s_a[j + 2], xb[(size_t)(j + 2) * DD + lane], a2);
        a3 = fmaf(s_a[j + 3], xb[(size_t)(j + 3) * DD + lane], a3);
    }
    part[wv][lane] = (a0 + a1) + (a2 + a3);
    __syncthreads();
    if (t < DD) s_agg[t] = part[0][t] + part[1][t] + part[2][t] + part[3][t];
    __syncthreads();

    // ---- projections + fp32 store + BN stats (threads 0..63, o = t) ----
    if (t < DD) {
        const int o = t;
        const float* __restrict__ w1 = W1 + o * DD;   // agg @ W_with.T
        const float* __restrict__ w2 = W2 + o * DD;   // x   @ W_without.T
        float v = b1[o] + b2[o];
        for (int d = 0; d < DD; ++d)
            v = fmaf(w1[d], s_agg[d], fmaf(w2[d], s_xi[d], v));
        xout[(size_t)blk * DD + o] = v;
        atomicAdd(&stats[o], v);
        atomicAdd(&stats[64 + o], v * v);
    }
}

// BN (batch stats, biased var) + selu -> fp32 out; float4 I/O.
__global__ __launch_bounds__(256) void final_kernel(
    const float* __restrict__ xout, const float* __restrict__ stats,
    const float* __restrict__ gamma, const float* __restrict__ beta,
    float* __restrict__ out)
{
    __shared__ float smu[DD], sga[DD], sbe[DD];
    if (threadIdx.x < DD) {
        const int o = threadIdx.x;
        const float mean = stats[o] * (1.0f / BN_ROWS);
        const float var  = stats[64 + o] * (1.0f / BN_ROWS) - mean * mean;
        smu[o] = mean;
        sga[o] = gamma[o] / sqrtf(var + 1e-5f);
        sbe[o] = beta[o];
    }
    __syncthreads();
    const int i4 = blockIdx.x * 256 + threadIdx.x;   // grid 512 -> exactly 131072
    const int o0 = (i4 & 15) * 4;
    const float4 v = ((const float4*)xout)[i4];
    float r[4] = { v.x, v.y, v.z, v.w };
    #pragma unroll
    for (int c = 0; c < 4; ++c) {
        const float nrm = (r[c] - smu[o0 + c]) * sga[o0 + c] + sbe[o0 + c];
        r[c] = nrm > 0.0f
            ? 1.0507009873554805f * nrm
            : 1.7580993408473766f * expm1f(nrm);
    }
    ((float4*)out)[i4] = make_float4(r[0], r[1], r[2], r[3]);
}

extern "C" void kernel_launch(void* const* d_in, const int* in_sizes, int n_in,
                              void* d_out, int out_size, void* d_ws, size_t ws_size,
                              hipStream_t stream)
{
    const float* x  = (const float*)d_in[0];
    const float* Wp = (const float*)d_in[1];  // W_att_proj
    const float* bp = (const float*)d_in[2];  // b_att_proj
    const float* aw = (const float*)d_in[3];  // att_weight
    const float* W1 = (const float*)d_in[4];  // W_with
    const float* b1 = (const float*)d_in[5];  // b_with
    const float* W2 = (const float*)d_in[6];  // W_without
    const float* b2 = (const float*)d_in[7];  // b_without
    const float* ga = (const float*)d_in[8];  // gamma
    const float* be = (const float*)d_in[9];  // beta

    float* xout  = (float*)d_ws;                        // 2 MB fp32
    float* stats = xout + (size_t)BN_ROWS * DD;         // 128 floats
    ushort* wpf  = (ushort*)(stats + 128);              // 4096 bf16 (frag order)
    float* out   = (float*)d_out;                       // fp32 output

    prep_kernel<<<16, 256, 0, stream>>>(Wp, wpf, stats);
    attn_kernel<<<BN_ROWS, 256, 0, stream>>>(x, wpf, bp, aw, W1, b1, W2, b2, xout, stats);
    final_kernel<<<512, 256, 0, stream>>>(xout, stats, ga, be, out);
}

// Round 16
// 294.807 us; speedup vs baseline: 2.1279x; 1.0098x over previous
//
#include <hip/hip_runtime.h>
#include <hip/hip_bf16.h>

#define BB 16
#define NN 512
#define DD 64
#define BN_ROWS (BB * NN)   // 8192

typedef unsigned short ushort;
typedef unsigned int uint;
typedef short bf16x8 __attribute__((ext_vector_type(8)));   // 8 bf16 = 4 VGPRs
typedef float f32x4  __attribute__((ext_vector_type(4)));   // MFMA acc

// ws layout: [0, 2MB) xout fp32 | [+512B) stats[128] | [+8KB) Wp bf16 frag-ordered

__device__ __forceinline__ short f2bf(float f) {
    union { float f; uint u; } c; c.f = f;
    const uint u = c.u;
    return (short)((u + 0x7fffu + ((u >> 16) & 1u)) >> 16);
}

// pack two fp32 -> two bf16 (round-half-up) in one v_perm_b32
__device__ __forceinline__ uint pkbf2(float lo, float hi) {
    union { float f; uint u; } a, b; a.f = lo; b.f = hi;
    return __builtin_amdgcn_perm(b.u + 0x8000u, a.u + 0x8000u, 0x07060302u);
}

__device__ __forceinline__ float fast_tanh(float x) {
    x = fminf(9.0f, fmaxf(-9.0f, x));
    const float e = __builtin_amdgcn_exp2f(x * 2.885390081777927f); // 2x*log2(e)
    return 1.0f - 2.0f * __builtin_amdgcn_rcpf(e + 1.0f);
}

// One-time: Wp -> bf16 in MFMA A-fragment order; zero BN stats.
__global__ __launch_bounds__(256) void prep_kernel(
    const float* __restrict__ Wp, ushort* __restrict__ wpf,
    float* __restrict__ stats)
{
    const int k = blockIdx.x * 256 + threadIdx.x;   // grid 16 -> 4096
    const int o = k >> 6, d = k & 63;
    const int mt = o >> 4, ln = o & 15;
    const int ks = d >> 5, qd = (d >> 3) & 3, e = d & 7;
    wpf[(((mt * 2 + ks) * 64) + (qd * 16 + ln)) * 8 + e] = (ushort)f2bf(Wp[k]);
    if (k < 128) stats[k] = 0.0f;
}

// One block per (b,i). Score GEMM via bf16 MFMA; A-frags + bias/aw from LDS.
__global__ __launch_bounds__(256, 3) void attn_kernel(
    const float* __restrict__ x,  const ushort* __restrict__ wpf,
    const float* __restrict__ bp, const float* __restrict__ aw,
    const float* __restrict__ W1, const float* __restrict__ b1,
    const float* __restrict__ W2, const float* __restrict__ b2,
    float* __restrict__ xout, float* __restrict__ stats)
{
    __shared__ __align__(16) ushort sWf[DD * DD];   // frag-ordered Wp bf16, 8 KB
    __shared__ __align__(16) float s_bp[DD], s_aw[DD], s_xi[DD];
    __shared__ float s_a[NN];
    __shared__ float wred[4];
    __shared__ float part[4][DD];
    __shared__ float s_agg[DD];

    const int blk = blockIdx.x;            // 0..8191
    const int b = blk >> 9;
    const int i = blk & (NN - 1);
    const int t = threadIdx.x;
    const float* __restrict__ xb = x + (size_t)b * NN * DD;

    {   // stage frag-ordered Wp (8 KB) as uint4 + small vectors
        const uint4* __restrict__ src = (const uint4*)wpf;
        uint4* __restrict__ dst = (uint4*)sWf;
        dst[t] = src[t];
        dst[t + 256] = src[t + 256];
    }
    if (t < DD) {
        s_bp[t] = bp[t];
        s_aw[t] = aw[t];
        s_xi[t] = xb[(size_t)i * DD + t];
    }
    __syncthreads();

    const int wv = t >> 6;           // wave 0..3 (owns j in [wv*128, wv*128+128))
    const int lane = t & 63;
    const int qd = lane >> 4;        // quad 0..3
    const int ln = lane & 15;

    float xiv[2][8];
    #pragma unroll
    for (int ks = 0; ks < 2; ++ks)
        #pragma unroll
        for (int e = 0; e < 8; ++e) xiv[ks][e] = s_xi[ks * 32 + qd * 8 + e];

    // ---- score GEMM: 4 pairs of n-tiles (2 x 16 j in flight) per wave ----
    #pragma unroll 2
    for (int np = 0; np < 4; ++np) {
        const int j0 = wv * 128 + np * 32 + ln;   // n-tile 2*np
        const int j1 = j0 + 16;                   // n-tile 2*np+1
        const float* __restrict__ xr0 = xb + (size_t)j0 * DD;
        const float* __restrict__ xr1 = xb + (size_t)j1 * DD;

        bf16x8 bf0[2], bf1[2];
        #pragma unroll
        for (int ks = 0; ks < 2; ++ks) {
            const float4 a0 = *(const float4*)(xr0 + ks * 32 + qd * 8);
            const float4 a1 = *(const float4*)(xr0 + ks * 32 + qd * 8 + 4);
            const float4 c0 = *(const float4*)(xr1 + ks * 32 + qd * 8);
            const float4 c1 = *(const float4*)(xr1 + ks * 32 + qd * 8 + 4);
            union { bf16x8 v; uint u[4]; } p, q;
            p.u[0] = pkbf2(a0.x * xiv[ks][0], a0.y * xiv[ks][1]);
            p.u[1] = pkbf2(a0.z * xiv[ks][2], a0.w * xiv[ks][3]);
            p.u[2] = pkbf2(a1.x * xiv[ks][4], a1.y * xiv[ks][5]);
            p.u[3] = pkbf2(a1.z * xiv[ks][6], a1.w * xiv[ks][7]);
            q.u[0] = pkbf2(c0.x * xiv[ks][0], c0.y * xiv[ks][1]);
            q.u[1] = pkbf2(c0.z * xiv[ks][2], c0.w * xiv[ks][3]);
            q.u[2] = pkbf2(c1.x * xiv[ks][4], c1.y * xiv[ks][5]);
            q.u[3] = pkbf2(c1.z * xiv[ks][6], c1.w * xiv[ks][7]);
            bf0[ks] = p.v;
            bf1[ks] = q.v;
        }

        float sj0 = 0.0f, sj1 = 0.0f;
        #pragma unroll
        for (int mt = 0; mt < 4; ++mt) {
            const bf16x8 af0 = *(const bf16x8*)(sWf + (((mt * 2 + 0) * 64) + lane) * 8);
            const bf16x8 af1 = *(const bf16x8*)(sWf + (((mt * 2 + 1) * 64) + lane) * 8);
            const float4 bp4 = *(const float4*)(s_bp + mt * 16 + qd * 4);  // broadcast
            const float4 aw4 = *(const float4*)(s_aw + mt * 16 + qd * 4);
            f32x4 acc0 = { bp4.x, bp4.y, bp4.z, bp4.w };
            f32x4 acc1 = acc0;
            acc0 = __builtin_amdgcn_mfma_f32_16x16x32_bf16(af0, bf0[0], acc0, 0, 0, 0);
            acc1 = __builtin_amdgcn_mfma_f32_16x16x32_bf16(af0, bf1[0], acc1, 0, 0, 0);
            acc0 = __builtin_amdgcn_mfma_f32_16x16x32_bf16(af1, bf0[1], acc0, 0, 0, 0);
            acc1 = __builtin_amdgcn_mfma_f32_16x16x32_bf16(af1, bf1[1], acc1, 0, 0, 0);
            sj0 = fmaf(aw4.x, fast_tanh(acc0[0]), sj0);
            sj1 = fmaf(aw4.x, fast_tanh(acc1[0]), sj1);
            sj0 = fmaf(aw4.y, fast_tanh(acc0[1]), sj0);
            sj1 = fmaf(aw4.y, fast_tanh(acc1[1]), sj1);
            sj0 = fmaf(aw4.z, fast_tanh(acc0[2]), sj0);
            sj1 = fmaf(aw4.z, fast_tanh(acc1[2]), sj1);
            sj0 = fmaf(aw4.w, fast_tanh(acc0[3]), sj0);
            sj1 = fmaf(aw4.w, fast_tanh(acc1[3]), sj1);
        }
        sj0 += __shfl_xor(sj0, 16);  sj1 += __shfl_xor(sj1, 16);
        sj0 += __shfl_xor(sj0, 32);  sj1 += __shfl_xor(sj1, 32);
        if (qd == 0) { s_a[j0] = sj0; s_a[j1] = sj1; }
    }
    __syncthreads();

    // ---- softmax over 512 scores: shuffle reduce, 3 barriers ----
    const float s0 = s_a[t], s1 = s_a[t + 256];
    float m = fmaxf(s0, s1);
    #pragma unroll
    for (int off = 1; off < 64; off <<= 1) m = fmaxf(m, __shfl_xor(m, off));
    if (lane == 0) wred[wv] = m;
    __syncthreads();
    const float gmax = fmaxf(fmaxf(wred[0], wred[1]), fmaxf(wred[2], wred[3]));
    __syncthreads();
    const float e0 = __builtin_amdgcn_exp2f((s0 - gmax) * 1.4426950408889634f);
    const float e1 = __builtin_amdgcn_exp2f((s1 - gmax) * 1.4426950408889634f);
    float sm = e0 + e1;
    #pragma unroll
    for (int off = 1; off < 64; off <<= 1) sm += __shfl_xor(sm, off);
    if (lane == 0) wred[wv] = sm;
    __syncthreads();
    const float inv = 1.0f / (wred[0] + wred[1] + wred[2] + wred[3]);
    s_a[t] = e0 * inv;
    s_a[t + 256] = e1 * inv;
    __syncthreads();

    // ---- aggregate: wave wv covers 128 j's; lane = channel d; 4-way ILP ----
    float a0 = 0.0f, a1 = 0.0f, a2 = 0.0f, a3 = 0.0f;
    for (int jj = 0; jj < 128; jj += 4) {
        const int j = wv * 128 + jj;
        a0 = fmaf(s_a[j],     xb[(size_t)(j)     * DD + lane], a0);
        a1 = fmaf(s_a[j + 1], xb[(size_t)(j + 1) * DD + lane], a1);
        a2 = fmaf(s_a[j + 2], xb[(size_t)(j + 2) * DD + lane], a2);
        a3 = fmaf(s_a[j + 3], xb[(size_t)(j + 3) * DD + lane], a3);
    }
    part[wv][lane] = (a0 + a1) + (a2 + a3);
    __syncthreads();
    if (t < DD) s_agg[t] = part[0][t] + part[1][t] + part[2][t] + part[3][t];
    __syncthreads();

    // ---- projections: all 256 threads; thread (o, q) sums 16 d's ----
    {
        const int o = t & 63, q = t >> 6;
        const float* __restrict__ w1 = W1 + o * DD + q * 16;
        const float* __restrict__ w2 = W2 + o * DD + q * 16;
        const float* __restrict__ ag = s_agg + q * 16;
        const float* __restrict__ xi = s_xi + q * 16;
        float v = 0.0f;
        #pragma unroll
        for (int d = 0; d < 16; ++d)
            v = fmaf(w1[d], ag[d], fmaf(w2[d], xi[d], v));
        part[q][o] = v;                 // reuse part[]
    }
    __syncthreads();
    if (t < DD) {
        const int o = t;
        const float v = b1[o] + b2[o] +
                        (part[0][o] + part[1][o]) + (part[2][o] + part[3][o]);
        xout[(size_t)blk * DD + o] = v;
        atomicAdd(&stats[o], v);
        atomicAdd(&stats[64 + o], v * v);
    }
}

// BN (batch stats, biased var) + selu -> fp32 out; float4 I/O.
__global__ __launch_bounds__(256) void final_kernel(
    const float* __restrict__ xout, const float* __restrict__ stats,
    const float* __restrict__ gamma, const float* __restrict__ beta,
    float* __restrict__ out)
{
    __shared__ float smu[DD], sga[DD], sbe[DD];
    if (threadIdx.x < DD) {
        const int o = threadIdx.x;
        const float mean = stats[o] * (1.0f / BN_ROWS);
        const float var  = stats[64 + o] * (1.0f / BN_ROWS) - mean * mean;
        smu[o] = mean;
        sga[o] = gamma[o] / sqrtf(var + 1e-5f);
        sbe[o] = beta[o];
    }
    __syncthreads();
    const int i4 = blockIdx.x * 256 + threadIdx.x;   // grid 512 -> exactly 131072
    const int o0 = (i4 & 15) * 4;
    const float4 v = ((const float4*)xout)[i4];
    float r[4] = { v.x, v.y, v.z, v.w };
    #pragma unroll
    for (int c = 0; c < 4; ++c) {
        const float nrm = (r[c] - smu[o0 + c]) * sga[o0 + c] + sbe[o0 + c];
        r[c] = nrm > 0.0f
            ? 1.0507009873554805f * nrm
            : 1.7580993408473766f * expm1f(nrm);
    }
    ((float4*)out)[i4] = make_float4(r[0], r[1], r[2], r[3]);
}

extern "C" void kernel_launch(void* const* d_in, const int* in_sizes, int n_in,
                              void* d_out, int out_size, void* d_ws, size_t ws_size,
                              hipStream_t stream)
{
    const float* x  = (const float*)d_in[0];
    const float* Wp = (const float*)d_in[1];  // W_att_proj
    const float* bp = (const float*)d_in[2];  // b_att_proj
    const float* aw = (const float*)d_in[3];  // att_weight
    const float* W1 = (const float*)d_in[4];  // W_with
    const float* b1 = (const float*)d_in[5];  // b_with
    const float* W2 = (const float*)d_in[6];  // W_without
    const float* b2 = (const float*)d_in[7];  // b_without
    const float* ga = (const float*)d_in[8];  // gamma
    const float* be = (const float*)d_in[9];  // beta

    float* xout  = (float*)d_ws;                        // 2 MB fp32
    float* stats = xout + (size_t)BN_ROWS * DD;         // 128 floats
    ushort* wpf  = (ushort*)(stats + 128);              // 4096 bf16 (frag order)
    float* out   = (float*)d_out;                       // fp32 output

    prep_kernel<<<16, 256, 0, stream>>>(Wp, wpf, stats);
    attn_kernel<<<BN_ROWS, 256, 0, stream>>>(x, wpf, bp, aw, W1, b1, W2, b2, xout, stats);
    final_kernel<<<512, 256, 0, stream>>>(xout, stats, ga, be, out);
}

// Round 17
// 291.797 us; speedup vs baseline: 2.1499x; 1.0103x over previous
//
#include <hip/hip_runtime.h>
#include <hip/hip_bf16.h>

#define BB 16
#define NN 512
#define DD 64
#define BN_ROWS (BB * NN)   // 8192

typedef unsigned short ushort;
typedef unsigned int uint;
typedef short bf16x8 __attribute__((ext_vector_type(8)));   // 8 bf16 = 4 VGPRs
typedef float f32x4  __attribute__((ext_vector_type(4)));   // MFMA acc

// ws layout: [0, 2MB) xout fp32 | [+512B) stats[128] | [+8KB) Wp bf16 frag-ordered

__device__ __forceinline__ short f2bf(float f) {
    union { float f; uint u; } c; c.f = f;
    const uint u = c.u;
    return (short)((u + 0x7fffu + ((u >> 16) & 1u)) >> 16);
}

// pack two fp32 -> two bf16 (round-half-up) in one v_perm_b32
__device__ __forceinline__ uint pkbf2(float lo, float hi) {
    union { float f; uint u; } a, b; a.f = lo; b.f = hi;
    return __builtin_amdgcn_perm(b.u + 0x8000u, a.u + 0x8000u, 0x07060302u);
}

__device__ __forceinline__ float fast_tanh(float x) {
    x = fminf(9.0f, fmaxf(-9.0f, x));
    const float e = __builtin_amdgcn_exp2f(x * 2.885390081777927f); // 2x*log2(e)
    return 1.0f - 2.0f * __builtin_amdgcn_rcpf(e + 1.0f);
}

// One-time: Wp -> bf16 in MFMA A-fragment order; zero BN stats.
__global__ __launch_bounds__(256) void prep_kernel(
    const float* __restrict__ Wp, ushort* __restrict__ wpf,
    float* __restrict__ stats)
{
    const int k = blockIdx.x * 256 + threadIdx.x;   // grid 16 -> 4096
    const int o = k >> 6, d = k & 63;
    const int mt = o >> 4, ln = o & 15;
    const int ks = d >> 5, qd = (d >> 3) & 3, e = d & 7;
    wpf[(((mt * 2 + ks) * 64) + (qd * 16 + ln)) * 8 + e] = (ushort)f2bf(Wp[k]);
    if (k < 128) stats[k] = 0.0f;
}

// One block (512 threads, 8 waves) per (b,i). Wave wv owns j in [wv*64, wv*64+64).
__global__ __launch_bounds__(512, 4) void attn_kernel(
    const float* __restrict__ x,  const ushort* __restrict__ wpf,
    const float* __restrict__ bp, const float* __restrict__ aw,
    const float* __restrict__ W1, const float* __restrict__ b1,
    const float* __restrict__ W2, const float* __restrict__ b2,
    float* __restrict__ xout, float* __restrict__ stats)
{
    __shared__ __align__(16) ushort sWf[DD * DD];   // frag-ordered Wp bf16, 8 KB
    __shared__ __align__(16) float s_bp[DD], s_aw[DD], s_xi[DD];
    __shared__ float s_a[NN];
    __shared__ float wred[8];
    __shared__ float part[8][DD];
    __shared__ float s_agg[DD];

    const int blk = blockIdx.x;            // 0..8191
    const int b = blk >> 9;
    const int i = blk & (NN - 1);
    const int t = threadIdx.x;             // 0..511
    const float* __restrict__ xb = x + (size_t)b * NN * DD;

    ((uint4*)sWf)[t] = ((const uint4*)wpf)[t];   // 512 x 16B = 8 KB
    if (t < DD) {
        s_bp[t] = bp[t];
        s_aw[t] = aw[t];
        s_xi[t] = xb[(size_t)i * DD + t];
    }
    __syncthreads();

    const int wv = t >> 6;           // wave 0..7
    const int lane = t & 63;
    const int qd = lane >> 4;        // quad 0..3
    const int ln = lane & 15;

    float xiv[2][8];
    #pragma unroll
    for (int ks = 0; ks < 2; ++ks)
        #pragma unroll
        for (int e = 0; e < 8; ++e) xiv[ks][e] = s_xi[ks * 32 + qd * 8 + e];

    // ---- score GEMM: 2 pairs of n-tiles (2 x 16 j in flight) per wave ----
    #pragma unroll
    for (int np = 0; np < 2; ++np) {
        const int j0 = wv * 64 + np * 32 + ln;
        const int j1 = j0 + 16;
        const float* __restrict__ xr0 = xb + (size_t)j0 * DD;
        const float* __restrict__ xr1 = xb + (size_t)j1 * DD;

        bf16x8 bf0[2], bf1[2];
        #pragma unroll
        for (int ks = 0; ks < 2; ++ks) {
            const float4 a0 = *(const float4*)(xr0 + ks * 32 + qd * 8);
            const float4 a1 = *(const float4*)(xr0 + ks * 32 + qd * 8 + 4);
            const float4 c0 = *(const float4*)(xr1 + ks * 32 + qd * 8);
            const float4 c1 = *(const float4*)(xr1 + ks * 32 + qd * 8 + 4);
            union { bf16x8 v; uint u[4]; } p, q;
            p.u[0] = pkbf2(a0.x * xiv[ks][0], a0.y * xiv[ks][1]);
            p.u[1] = pkbf2(a0.z * xiv[ks][2], a0.w * xiv[ks][3]);
            p.u[2] = pkbf2(a1.x * xiv[ks][4], a1.y * xiv[ks][5]);
            p.u[3] = pkbf2(a1.z * xiv[ks][6], a1.w * xiv[ks][7]);
            q.u[0] = pkbf2(c0.x * xiv[ks][0], c0.y * xiv[ks][1]);
            q.u[1] = pkbf2(c0.z * xiv[ks][2], c0.w * xiv[ks][3]);
            q.u[2] = pkbf2(c1.x * xiv[ks][4], c1.y * xiv[ks][5]);
            q.u[3] = pkbf2(c1.z * xiv[ks][6], c1.w * xiv[ks][7]);
            bf0[ks] = p.v;
            bf1[ks] = q.v;
        }

        float sj0 = 0.0f, sj1 = 0.0f;
        #pragma unroll
        for (int mt = 0; mt < 4; ++mt) {
            const bf16x8 af0 = *(const bf16x8*)(sWf + (((mt * 2 + 0) * 64) + lane) * 8);
            const bf16x8 af1 = *(const bf16x8*)(sWf + (((mt * 2 + 1) * 64) + lane) * 8);
            const float4 bp4 = *(const float4*)(s_bp + mt * 16 + qd * 4);  // broadcast
            const float4 aw4 = *(const float4*)(s_aw + mt * 16 + qd * 4);
            f32x4 acc0 = { bp4.x, bp4.y, bp4.z, bp4.w };
            f32x4 acc1 = acc0;
            acc0 = __builtin_amdgcn_mfma_f32_16x16x32_bf16(af0, bf0[0], acc0, 0, 0, 0);
            acc1 = __builtin_amdgcn_mfma_f32_16x16x32_bf16(af0, bf1[0], acc1, 0, 0, 0);
            acc0 = __builtin_amdgcn_mfma_f32_16x16x32_bf16(af1, bf0[1], acc0, 0, 0, 0);
            acc1 = __builtin_amdgcn_mfma_f32_16x16x32_bf16(af1, bf1[1], acc1, 0, 0, 0);
            sj0 = fmaf(aw4.x, fast_tanh(acc0[0]), sj0);
            sj1 = fmaf(aw4.x, fast_tanh(acc1[0]), sj1);
            sj0 = fmaf(aw4.y, fast_tanh(acc0[1]), sj0);
            sj1 = fmaf(aw4.y, fast_tanh(acc1[1]), sj1);
            sj0 = fmaf(aw4.z, fast_tanh(acc0[2]), sj0);
            sj1 = fmaf(aw4.z, fast_tanh(acc1[2]), sj1);
            sj0 = fmaf(aw4.w, fast_tanh(acc0[3]), sj0);
            sj1 = fmaf(aw4.w, fast_tanh(acc1[3]), sj1);
        }
        sj0 += __shfl_xor(sj0, 16);  sj1 += __shfl_xor(sj1, 16);
        sj0 += __shfl_xor(sj0, 32);  sj1 += __shfl_xor(sj1, 32);
        if (qd == 0) { s_a[j0] = sj0; s_a[j1] = sj1; }
    }
    __syncthreads();

    // ---- softmax, no max-pass (|s| <= sum|aw| ~ 9, exp fp32-safe) ----
    const float e0 = __builtin_amdgcn_exp2f(s_a[t] * 1.4426950408889634f);
    float sm = e0;
    #pragma unroll
    for (int off = 1; off < 64; off <<= 1) sm += __shfl_xor(sm, off);
    if (lane == 0) wred[wv] = sm;
    __syncthreads();
    const float total = (wred[0] + wred[1]) + (wred[2] + wred[3])
                      + (wred[4] + wred[5]) + (wred[6] + wred[7]);
    const float inv = 1.0f / total;
    s_a[t] = e0 * inv;
    __syncthreads();

    // ---- aggregate: wave wv covers 64 j's; lane = channel d; 8-way ILP ----
    {
        float a0 = 0, a1 = 0, a2 = 0, a3 = 0, a4 = 0, a5 = 0, a6 = 0, a7 = 0;
        const int j = wv * 64;
        #pragma unroll
        for (int jj = 0; jj < 64; jj += 8) {
            a0 = fmaf(s_a[j + jj],     xb[(size_t)(j + jj)     * DD + lane], a0);
            a1 = fmaf(s_a[j + jj + 1], xb[(size_t)(j + jj + 1) * DD + lane], a1);
            a2 = fmaf(s_a[j + jj + 2], xb[(size_t)(j + jj + 2) * DD + lane], a2);
            a3 = fmaf(s_a[j + jj + 3], xb[(size_t)(j + jj + 3) * DD + lane], a3);
            a4 = fmaf(s_a[j + jj + 4], xb[(size_t)(j + jj + 4) * DD + lane], a4);
            a5 = fmaf(s_a[j + jj + 5], xb[(size_t)(j + jj + 5) * DD + lane], a5);
            a6 = fmaf(s_a[j + jj + 6], xb[(size_t)(j + jj + 6) * DD + lane], a6);
            a7 = fmaf(s_a[j + jj + 7], xb[(size_t)(j + jj + 7) * DD + lane], a7);
        }
        part[wv][lane] = ((a0 + a1) + (a2 + a3)) + ((a4 + a5) + (a6 + a7));
    }
    __syncthreads();
    if (t < DD) {
        s_agg[t] = ((part[0][t] + part[1][t]) + (part[2][t] + part[3][t]))
                 + ((part[4][t] + part[5][t]) + (part[6][t] + part[7][t]));
    }
    __syncthreads();

    // ---- projections: 512 threads; thread (o, q) sums 8 d's ----
    {
        const int o = t & 63, q = t >> 6;
        const float4 w1a = *(const float4*)(W1 + o * DD + q * 8);
        const float4 w1b = *(const float4*)(W1 + o * DD + q * 8 + 4);
        const float4 w2a = *(const float4*)(W2 + o * DD + q * 8);
        const float4 w2b = *(const float4*)(W2 + o * DD + q * 8 + 4);
        const float4 aga = *(const float4*)(s_agg + q * 8);
        const float4 agb = *(const float4*)(s_agg + q * 8 + 4);
        const float4 xia = *(const float4*)(s_xi + q * 8);
        const float4 xib = *(const float4*)(s_xi + q * 8 + 4);
        float v = 0.0f;
        v = fmaf(w1a.x, aga.x, fmaf(w2a.x, xia.x, v));
        v = fmaf(w1a.y, aga.y, fmaf(w2a.y, xia.y, v));
        v = fmaf(w1a.z, aga.z, fmaf(w2a.z, xia.z, v));
        v = fmaf(w1a.w, aga.w, fmaf(w2a.w, xia.w, v));
        v = fmaf(w1b.x, agb.x, fmaf(w2b.x, xib.x, v));
        v = fmaf(w1b.y, agb.y, fmaf(w2b.y, xib.y, v));
        v = fmaf(w1b.z, agb.z, fmaf(w2b.z, xib.z, v));
        v = fmaf(w1b.w, agb.w, fmaf(w2b.w, xib.w, v));
        part[q][o] = v;
    }
    __syncthreads();
    if (t < DD) {
        const int o = t;
        const float v = b1[o] + b2[o]
            + ((part[0][o] + part[1][o]) + (part[2][o] + part[3][o]))
            + ((part[4][o] + part[5][o]) + (part[6][o] + part[7][o]));
        xout[(size_t)blk * DD + o] = v;
        atomicAdd(&stats[o], v);
        atomicAdd(&stats[64 + o], v * v);
    }
}

// BN (batch stats, biased var) + selu -> fp32 out; float4 I/O.
__global__ __launch_bounds__(256) void final_kernel(
    const float* __restrict__ xout, const float* __restrict__ stats,
    const float* __restrict__ gamma, const float* __restrict__ beta,
    float* __restrict__ out)
{
    __shared__ float smu[DD], sga[DD], sbe[DD];
    if (threadIdx.x < DD) {
        const int o = threadIdx.x;
        const float mean = stats[o] * (1.0f / BN_ROWS);
        const float var  = stats[64 + o] * (1.0f / BN_ROWS) - mean * mean;
        smu[o] = mean;
        sga[o] = gamma[o] / sqrtf(var + 1e-5f);
        sbe[o] = beta[o];
    }
    __syncthreads();
    const int i4 = blockIdx.x * 256 + threadIdx.x;   // grid 512 -> exactly 131072
    const int o0 = (i4 & 15) * 4;
    const float4 v = ((const float4*)xout)[i4];
    float r[4] = { v.x, v.y, v.z, v.w };
    #pragma unroll
    for (int c = 0; c < 4; ++c) {
        const float nrm = (r[c] - smu[o0 + c]) * sga[o0 + c] + sbe[o0 + c];
        r[c] = nrm > 0.0f
            ? 1.0507009873554805f * nrm
            : 1.7580993408473766f * expm1f(nrm);
    }
    ((float4*)out)[i4] = make_float4(r[0], r[1], r[2], r[3]);
}

extern "C" void kernel_launch(void* const* d_in, const int* in_sizes, int n_in,
                              void* d_out, int out_size, void* d_ws, size_t ws_size,
                              hipStream_t stream)
{
    const float* x  = (const float*)d_in[0];
    const float* Wp = (const float*)d_in[1];  // W_att_proj
    const float* bp = (const float*)d_in[2];  // b_att_proj
    const float* aw = (const float*)d_in[3];  // att_weight
    const float* W1 = (const float*)d_in[4];  // W_with
    const float* b1 = (const float*)d_in[5];  // b_with
    const float* W2 = (const float*)d_in[6];  // W_without
    const float* b2 = (const float*)d_in[7];  // b_without
    const float* ga = (const float*)d_in[8];  // gamma
    const float* be = (const float*)d_in[9];  // beta

    float* xout  = (float*)d_ws;                        // 2 MB fp32
    float* stats = xout + (size_t)BN_ROWS * DD;         // 128 floats
    ushort* wpf  = (ushort*)(stats + 128);              // 4096 bf16 (frag order)
    float* out   = (float*)d_out;                       // fp32 output

    prep_kernel<<<16, 256, 0, stream>>>(Wp, wpf, stats);
    attn_kernel<<<BN_ROWS, 512, 0, stream>>>(x, wpf, bp, aw, W1, b1, W2, b2, xout, stats);
    final_kernel<<<512, 256, 0, stream>>>(xout, stats, ga, be, out);
}

// Round 18
// 290.552 us; speedup vs baseline: 2.1591x; 1.0043x over previous
//
#include <hip/hip_runtime.h>
#include <hip/hip_bf16.h>

#define BB 16
#define NN 512
#define DD 64
#define BN_ROWS (BB * NN)   // 8192

typedef unsigned short ushort;
typedef unsigned int uint;
typedef short bf16x8 __attribute__((ext_vector_type(8)));   // 8 bf16 = 4 VGPRs
typedef float f32x4  __attribute__((ext_vector_type(4)));   // MFMA acc

// ws layout: stats[128] | wpf fp32 frag-ordered [4096] | xbf bf16 frag-ordered [524288]
// Key identity: Wp·(xi⊙xj) = (Wp⊙xi)·xj  →  A-frag = Wp·xi (built once per block),
// B-frag = xj bf16 (pre-converted once per LAUNCH in prep; i-independent).

// pack two fp32 -> two bf16 (round-half-up) in one v_perm_b32
__device__ __forceinline__ uint pkbf2(float lo, float hi) {
    union { float f; uint u; } a, b; a.f = lo; b.f = hi;
    return __builtin_amdgcn_perm(b.u + 0x8000u, a.u + 0x8000u, 0x07060302u);
}
__device__ __forceinline__ float bflo(uint u) {
    union { uint i; float f; } c; c.i = u << 16; return c.f;
}
__device__ __forceinline__ float bfhi(uint u) {
    union { uint i; float f; } c; c.i = u & 0xffff0000u; return c.f;
}

__device__ __forceinline__ float fast_tanh(float x) {
    x = fminf(9.0f, fmaxf(-9.0f, x));
    const float e = __builtin_amdgcn_exp2f(x * 2.885390081777927f); // 2x*log2(e)
    return 1.0f - 2.0f * __builtin_amdgcn_rcpf(e + 1.0f);
}

// One-time: x -> bf16 B-frag order; Wp -> fp32 A-frag order; zero stats.
// xbf addr tid*8+e holds x[b][jt*16+ln][ks*32+qd*8+e], tid=((b*32+jt)*2+ks)*64+lane.
__global__ __launch_bounds__(256) void prep_kernel(
    const float* __restrict__ x, const float* __restrict__ Wp,
    float* __restrict__ wpf, ushort* __restrict__ xbf, float* __restrict__ stats)
{
    const int tid = blockIdx.x * 256 + threadIdx.x;     // grid 256 -> 0..65535
    const int b = tid >> 12, rem = tid & 4095;
    const int jt = rem >> 7, ks = (rem >> 6) & 1, lane = rem & 63;
    const int qd = lane >> 4, ln = lane & 15;
    const float* __restrict__ src =
        x + ((size_t)(b * NN + jt * 16 + ln)) * DD + ks * 32 + qd * 8;
    const float4 v0 = *(const float4*)src;
    const float4 v1 = *(const float4*)(src + 4);
    uint4 o;
    o.x = pkbf2(v0.x, v0.y); o.y = pkbf2(v0.z, v0.w);
    o.z = pkbf2(v1.x, v1.y); o.w = pkbf2(v1.z, v1.w);
    ((uint4*)xbf)[tid] = o;                              // coalesced
    if (tid < DD * DD) {
        const int oo = tid >> 6, d = tid & 63;
        const int mt = oo >> 4, l2 = oo & 15;
        const int k2 = d >> 5, q2 = (d >> 3) & 3, e = d & 7;
        wpf[(((mt * 2 + k2) * 64) + (q2 * 16 + l2)) * 8 + e] = Wp[tid];
    }
    if (tid < 128) stats[tid] = 0.0f;
}

// One block (512 threads, 8 waves) per (b,i). Wave wv owns j in [wv*64, wv*64+64).
__global__ __launch_bounds__(512, 4) void attn_kernel(
    const float* __restrict__ x,  const float* __restrict__ wpf,
    const ushort* __restrict__ xbf,
    const float* __restrict__ bp, const float* __restrict__ aw,
    const float* __restrict__ W1, const float* __restrict__ b1,
    const float* __restrict__ W2, const float* __restrict__ b2,
    float* __restrict__ out, float* __restrict__ stats)
{
    __shared__ __align__(16) float s_bp[DD], s_aw[DD], s_xi[DD];
    __shared__ float s_a[NN];
    __shared__ float wred[8];
    __shared__ float part[8][DD];
    __shared__ float s_agg[DD];

    const int blk = blockIdx.x;            // 0..8191
    const int b = blk >> 9;
    const int i = blk & (NN - 1);
    const int t = threadIdx.x;             // 0..511
    const ushort* __restrict__ xb16 = xbf + (size_t)b * (NN * DD);  // 32 KB per b

    if (t < DD) {
        s_bp[t] = bp[t];
        s_aw[t] = aw[t];
        s_xi[t] = x[((size_t)(b * NN + i)) * DD + t];
    }
    __syncthreads();

    const int wv = t >> 6, lane = t & 63, qd = lane >> 4, ln = lane & 15;

    float xiv[2][8];
    #pragma unroll
    for (int ks = 0; ks < 2; ++ks)
        #pragma unroll
        for (int e = 0; e < 8; ++e) xiv[ks][e] = s_xi[ks * 32 + qd * 8 + e];

    // A-frags: Wi = Wp * xi, bf16, built once per block (g = mt*2+ks)
    bf16x8 afrag[8];
    #pragma unroll
    for (int g = 0; g < 8; ++g) {
        const int ks = g & 1;
        const float4 wa = *(const float4*)(wpf + (g * 64 + lane) * 8);
        const float4 wb = *(const float4*)(wpf + (g * 64 + lane) * 8 + 4);
        union { bf16x8 v; uint u[4]; } p;
        p.u[0] = pkbf2(wa.x * xiv[ks][0], wa.y * xiv[ks][1]);
        p.u[1] = pkbf2(wa.z * xiv[ks][2], wa.w * xiv[ks][3]);
        p.u[2] = pkbf2(wb.x * xiv[ks][4], wb.y * xiv[ks][5]);
        p.u[3] = pkbf2(wb.z * xiv[ks][6], wb.w * xiv[ks][7]);
        afrag[g] = p.v;
    }

    // ---- score: 4 j-tiles per wave; B-frag = plain 16B load ----
    #pragma unroll
    for (int tt = 0; tt < 4; ++tt) {
        const int jt = wv * 4 + tt;
        const bf16x8 bf0 = *(const bf16x8*)(xb16 + ((jt * 2 + 0) * 64 + lane) * 8);
        const bf16x8 bf1 = *(const bf16x8*)(xb16 + ((jt * 2 + 1) * 64 + lane) * 8);
        float s0 = 0.0f, s1 = 0.0f, s2 = 0.0f, s3 = 0.0f;
        #pragma unroll
        for (int mt = 0; mt < 4; ++mt) {
            const float4 bp4 = *(const float4*)(s_bp + mt * 16 + qd * 4);  // broadcast
            const float4 aw4 = *(const float4*)(s_aw + mt * 16 + qd * 4);
            f32x4 acc = { bp4.x, bp4.y, bp4.z, bp4.w };
            acc = __builtin_amdgcn_mfma_f32_16x16x32_bf16(afrag[mt*2+0], bf0, acc, 0, 0, 0);
            acc = __builtin_amdgcn_mfma_f32_16x16x32_bf16(afrag[mt*2+1], bf1, acc, 0, 0, 0);
            s0 = fmaf(aw4.x, fast_tanh(acc[0]), s0);
            s1 = fmaf(aw4.y, fast_tanh(acc[1]), s1);
            s2 = fmaf(aw4.z, fast_tanh(acc[2]), s2);
            s3 = fmaf(aw4.w, fast_tanh(acc[3]), s3);
        }
        float sj = (s0 + s1) + (s2 + s3);
        sj += __shfl_xor(sj, 16);
        sj += __shfl_xor(sj, 32);
        if (qd == 0) s_a[jt * 16 + ln] = sj;
    }
    __syncthreads();

    // ---- softmax, no max-pass (|s| <= sum|aw| ~ 9, exp fp32-safe) ----
    const float e0 = __builtin_amdgcn_exp2f(s_a[t] * 1.4426950408889634f);
    float sm = e0;
    #pragma unroll
    for (int off = 1; off < 64; off <<= 1) sm += __shfl_xor(sm, off);
    if (lane == 0) wred[wv] = sm;
    __syncthreads();
    const float inv = 1.0f / ((wred[0] + wred[1]) + (wred[2] + wred[3])
                            + (wred[4] + wred[5]) + (wred[6] + wred[7]));
    s_a[t] = e0 * inv;
    __syncthreads();

    // ---- aggregate from xbf frags: 8 loads/lane, shfl-tree over ln ----
    float vacc[16];
    #pragma unroll
    for (int k = 0; k < 16; ++k) vacc[k] = 0.0f;
    #pragma unroll
    for (int tt = 0; tt < 4; ++tt) {
        const int jt = wv * 4 + tt;
        const float aj = s_a[jt * 16 + ln];
        #pragma unroll
        for (int ks = 0; ks < 2; ++ks) {
            const uint4 u = *(const uint4*)(xb16 + ((jt * 2 + ks) * 64 + lane) * 8);
            vacc[ks*8+0] = fmaf(aj, bflo(u.x), vacc[ks*8+0]);
            vacc[ks*8+1] = fmaf(aj, bfhi(u.x), vacc[ks*8+1]);
            vacc[ks*8+2] = fmaf(aj, bflo(u.y), vacc[ks*8+2]);
            vacc[ks*8+3] = fmaf(aj, bfhi(u.y), vacc[ks*8+3]);
            vacc[ks*8+4] = fmaf(aj, bflo(u.z), vacc[ks*8+4]);
            vacc[ks*8+5] = fmaf(aj, bfhi(u.z), vacc[ks*8+5]);
            vacc[ks*8+6] = fmaf(aj, bflo(u.w), vacc[ks*8+6]);
            vacc[ks*8+7] = fmaf(aj, bfhi(u.w), vacc[ks*8+7]);
        }
    }
    #pragma unroll
    for (int off = 1; off < 16; off <<= 1)
        #pragma unroll
        for (int k = 0; k < 16; ++k)
            vacc[k] += __shfl_xor(vacc[k], off);
    if (ln == 0) {
        #pragma unroll
        for (int k = 0; k < 16; ++k)
            part[wv][(k >> 3) * 32 + qd * 8 + (k & 7)] = vacc[k];
    }
    __syncthreads();
    if (t < DD)
        s_agg[t] = ((part[0][t] + part[1][t]) + (part[2][t] + part[3][t]))
                 + ((part[4][t] + part[5][t]) + (part[6][t] + part[7][t]));
    __syncthreads();

    // ---- projections: 512 threads; thread (o, q) sums 8 d's ----
    {
        const int o = t & 63, q = t >> 6;
        const float4 w1a = *(const float4*)(W1 + o * DD + q * 8);
        const float4 w1b = *(const float4*)(W1 + o * DD + q * 8 + 4);
        const float4 w2a = *(const float4*)(W2 + o * DD + q * 8);
        const float4 w2b = *(const float4*)(W2 + o * DD + q * 8 + 4);
        const float4 aga = *(const float4*)(s_agg + q * 8);
        const float4 agb = *(const float4*)(s_agg + q * 8 + 4);
        const float4 xia = *(const float4*)(s_xi + q * 8);
        const float4 xib = *(const float4*)(s_xi + q * 8 + 4);
        float v = 0.0f;
        v = fmaf(w1a.x, aga.x, fmaf(w2a.x, xia.x, v));
        v = fmaf(w1a.y, aga.y, fmaf(w2a.y, xia.y, v));
        v = fmaf(w1a.z, aga.z, fmaf(w2a.z, xia.z, v));
        v = fmaf(w1a.w, aga.w, fmaf(w2a.w, xia.w, v));
        v = fmaf(w1b.x, agb.x, fmaf(w2b.x, xib.x, v));
        v = fmaf(w1b.y, agb.y, fmaf(w2b.y, xib.y, v));
        v = fmaf(w1b.z, agb.z, fmaf(w2b.z, xib.z, v));
        v = fmaf(w1b.w, agb.w, fmaf(w2b.w, xib.w, v));
        part[q][o] = v;
    }
    __syncthreads();
    if (t < DD) {
        const int o = t;
        const float v = b1[o] + b2[o]
            + ((part[0][o] + part[1][o]) + (part[2][o] + part[3][o]))
            + ((part[4][o] + part[5][o]) + (part[6][o] + part[7][o]));
        out[(size_t)blk * DD + o] = v;     // pre-BN x_out into d_out
        atomicAdd(&stats[o], v);
        atomicAdd(&stats[64 + o], v * v);
    }
}

// BN (batch stats, biased var) + selu, IN PLACE on out; float4 I/O.
__global__ __launch_bounds__(256) void final_kernel(
    const float* __restrict__ stats,
    const float* __restrict__ gamma, const float* __restrict__ beta,
    float* __restrict__ out)
{
    __shared__ float smu[DD], sga[DD], sbe[DD];
    if (threadIdx.x < DD) {
        const int o = threadIdx.x;
        const float mean = stats[o] * (1.0f / BN_ROWS);
        const float var  = stats[64 + o] * (1.0f / BN_ROWS) - mean * mean;
        smu[o] = mean;
        sga[o] = gamma[o] / sqrtf(var + 1e-5f);
        sbe[o] = beta[o];
    }
    __syncthreads();
    const int i4 = blockIdx.x * 256 + threadIdx.x;   // grid 512 -> exactly 131072
    const int o0 = (i4 & 15) * 4;
    const float4 v = ((const float4*)out)[i4];
    float r[4] = { v.x, v.y, v.z, v.w };
    #pragma unroll
    for (int c = 0; c < 4; ++c) {
        const float nrm = (r[c] - smu[o0 + c]) * sga[o0 + c] + sbe[o0 + c];
        r[c] = nrm > 0.0f
            ? 1.0507009873554805f * nrm
            : 1.7580993408473766f * expm1f(nrm);
    }
    ((float4*)out)[i4] = make_float4(r[0], r[1], r[2], r[3]);
}

extern "C" void kernel_launch(void* const* d_in, const int* in_sizes, int n_in,
                              void* d_out, int out_size, void* d_ws, size_t ws_size,
                              hipStream_t stream)
{
    const float* x  = (const float*)d_in[0];
    const float* Wp = (const float*)d_in[1];  // W_att_proj
    const float* bp = (const float*)d_in[2];  // b_att_proj
    const float* aw = (const float*)d_in[3];  // att_weight
    const float* W1 = (const float*)d_in[4];  // W_with
    const float* b1 = (const float*)d_in[5];  // b_with
    const float* W2 = (const float*)d_in[6];  // W_without
    const float* b2 = (const float*)d_in[7];  // b_without
    const float* ga = (const float*)d_in[8];  // gamma
    const float* be = (const float*)d_in[9];  // beta

    float*  stats = (float*)d_ws;                       // 128 floats
    float*  wpf   = stats + 128;                        // 4096 fp32 (A-frag order)
    ushort* xbf   = (ushort*)(wpf + DD * DD);           // 524288 bf16 (B-frag order)
    float*  out   = (float*)d_out;                      // fp32 output

    prep_kernel<<<256, 256, 0, stream>>>(x, Wp, wpf, xbf, stats);
    attn_kernel<<<BN_ROWS, 512, 0, stream>>>(x, wpf, xbf, bp, aw, W1, b1, W2, b2, out, stats);
    final_kernel<<<512, 256, 0, stream>>>(stats, ga, be, out);
}